// Round 11
// baseline (322.830 us; speedup 1.0000x reference)
//
#include <hip/hip_runtime.h>

typedef __attribute__((ext_vector_type(8))) short bf16x8;
typedef __attribute__((ext_vector_type(4))) float f32x4;

// Operand-swapped GEMM: D^T = W (A-operand) * h^T (B-operand).
// MERGED WAVE SPECIALIZATION: 8 waves = {L12, L3} x 4 col-stripes.
// L12 wave: reads h1 (shared by L1-state AND L2-input) + h2; computes L1(i)
// (6 MFMA) and L2(i-1) (12 MFMA). L3 wave: reads h2 + h3; computes L3(i-2).
// Cuts per-CU ds_read_b128 per phase from 96 to 64 (LDS drain is the wall).
#define MFMA(a, b, c) __builtin_amdgcn_mfma_f32_16x16x32_bf16((a), (b), (c), 0, 0, 0)

__device__ __forceinline__ short f2bf(float f) {
    union { float f; unsigned u; } v; v.f = f;
    unsigned r = v.u + 0x7fffu + ((v.u >> 16) & 1u);   // RNE
    return (short)(r >> 16);
}
__device__ __forceinline__ float bf2f(short h) {
    union { unsigned u; float f; } v;
    v.u = ((unsigned)(unsigned short)h) << 16;
    return v.f;
}
__device__ __forceinline__ void wsplit(float w, short& hi, short& lo) {
    hi = f2bf(w);
    lo = f2bf(w - bf2f(hi));
}
__device__ __forceinline__ float tanh_fast(float x) {
    float z = __builtin_amdgcn_exp2f(x * 2.8853900817779268f); // 2*log2(e)
    return 1.0f - 2.0f * __builtin_amdgcn_rcpf(z + 1.0f);
}
__device__ __forceinline__ unsigned cvt_pk_bf16(float a, float b) {
    unsigned r;
    asm("v_cvt_pk_bf16_f32 %0, %1, %2" : "=v"(r) : "v"(a), "v"(b));
    return r;
}

// weight fragment pair (hi + bf16 residual): element i = W[jrow][kbase+i], zero-padded
__device__ __forceinline__ void makeA2(const float* __restrict__ W, int jrow, int kbase,
                                       bf16x8& Ahi, bf16x8& Alo) {
#pragma unroll
    for (int i = 0; i < 8; ++i) {
        int m = kbase + i;
        short h = 0, l = 0;
        if (jrow < 50 && m < 50) wsplit(W[jrow * 50 + m], h, l);
        Ahi[i] = h; Alo[i] = l;
    }
}

// --- LDS h tile: [16 batch][128 hidden] bf16 (256B rows); cols 0-63 hi, 64-127 lo.
// XOR-swizzle bits 4-7 of byte-in-row with row (bijective).
// swz(row, b ^ 128) == swz(row, b) ^ 128 -> lo offset derived by XOR on the
// INTEGER offset (never +128, never XOR on a flat pointer).
__device__ __forceinline__ int swz(int row, int byteInRow) {
    return (row << 8) + (byteInRow ^ ((row & 15) << 4));
}
__device__ __forceinline__ bf16x8 ldsA(const short* buf, int row, int kblk, int g) {
    return *(const bf16x8*)((const char*)buf + swz(row, (kblk << 6) + (g << 4)));
}
__device__ __forceinline__ float ldsR(const short* buf, int row, int col) {
    return bf2f(*(const short*)((const char*)buf + swz(row, col << 1)));
}

// store 4 consecutive hidden cols (hi + lo residual) for this lane's batch row.
__device__ __forceinline__ void storeT(short* buf, int off, float t0, float t1, float t2, float t3) {
    unsigned h01 = cvt_pk_bf16(t0, t1);
    unsigned h23 = cvt_pk_bf16(t2, t3);
    float r0 = t0 - bf2f((short)h01);
    float r1 = t1 - bf2f((short)(h01 >> 16));
    float r2 = t2 - bf2f((short)h23);
    float r3 = t3 - bf2f((short)(h23 >> 16));
    unsigned l01 = cvt_pk_bf16(r0, r1);
    unsigned l23 = cvt_pk_bf16(r2, r3);
    uint2 hv; hv.x = h01; hv.y = h23;
    uint2 lv; lv.x = l01; lv.y = l23;
    *(uint2*)((char*)buf + off)         = hv;
    *(uint2*)((char*)buf + (off ^ 128)) = lv;
}
__device__ __forceinline__ void storeZ(short* buf, int off) {
    uint2 zz; zz.x = 0u; zz.y = 0u;
    *(uint2*)((char*)buf + off)         = zz;
    *(uint2*)((char*)buf + (off ^ 128)) = zz;
}

// One phase. Z2/Z3: force zero output for the full-layer store (pipeline fill).
// Reads parity-q arrays r*, writes parity-p arrays w*, ONE barrier at phase end.
// L12 wave (isL12): x-frags from r1 (h1: L1 state + L2 input), y-frags from r2
//   (h2: L2 state); A = Whh1, B = Wih2, C = Whh2; stores w1 (L1) + w2 (L2).
// L3 wave: x-frags from r2 (h2: input), y-frags from r3 (h3: state);
//   A = zeros (dummy chain, branch-free), B = Wih3, C = Whh3; stores w3.
template<bool Z2, bool Z3>
__device__ __forceinline__ void phaseM(
    const short* r1, const short* r2, const short* r3,
    short* w1, short* w2, short* w3,
    bool isL12, int bcol, int g, int wbyte, float xf,
    const f32x4& b1v, const f32x4& bFv, const f32x4& w1f,
    const bf16x8& Ah0, const bf16x8& Ah1, const bf16x8& Al0, const bf16x8& Al1,
    const bf16x8& Bh0, const bf16x8& Bh1, const bf16x8& Bl0, const bf16x8& Bl1,
    const bf16x8& Ch0, const bf16x8& Ch1, const bf16x8& Cl0, const bf16x8& Cl1,
    const f32x4& zc)
{
    const short* rX = isL12 ? r1 : r2;
    const short* rY = isL12 ? r2 : r3;
    bf16x8 x0 = ldsA(rX, bcol, 0, g), x1 = ldsA(rX, bcol, 1, g);
    bf16x8 x2 = ldsA(rX, bcol, 2, g), x3 = ldsA(rX, bcol, 3, g);
    bf16x8 y0 = ldsA(rY, bcol, 0, g), y1 = ldsA(rY, bcol, 1, g);
    bf16x8 y2 = ldsA(rY, bcol, 2, g), y3 = ldsA(rY, bcol, 3, g);

    f32x4 c1i;
    c1i[0] = fmaf(w1f[0], xf, b1v[0]);
    c1i[1] = fmaf(w1f[1], xf, b1v[1]);
    c1i[2] = fmaf(w1f[2], xf, b1v[2]);
    c1i[3] = fmaf(w1f[3], xf, b1v[3]);

    __builtin_amdgcn_s_setprio(1);
    // full layer (B on x, C on y): 4 chains of 3; L1/dummy (A on x): 3 chains of 2
    f32x4 a0 = MFMA(Bh0, x0, bFv);
    f32x4 a1 = MFMA(Ch0, y0, zc);
    f32x4 a2 = MFMA(Bh0, x2, zc);
    f32x4 a3 = MFMA(Ch0, y2, zc);
    f32x4 u0 = MFMA(Ah0, x0, c1i);
    f32x4 u1 = MFMA(Ah0, x2, zc);
    f32x4 u2 = MFMA(Al0, x0, zc);
    a0 = MFMA(Bh1, x1, a0);
    a1 = MFMA(Ch1, y1, a1);
    a2 = MFMA(Bh1, x3, a2);
    a3 = MFMA(Ch1, y3, a3);
    u0 = MFMA(Ah1, x1, u0);
    u1 = MFMA(Ah1, x3, u1);
    u2 = MFMA(Al1, x1, u2);
    a0 = MFMA(Cl0, y0, a0);
    a1 = MFMA(Bl0, x0, a1);
    a2 = MFMA(Cl1, y1, a2);
    a3 = MFMA(Bl1, x1, a3);
    __builtin_amdgcn_s_setprio(0);

    if (isL12) {
        // L2(i-1) output
        if (Z2) {
            storeZ(w2, wbyte);
        } else {
            float t0 = tanh_fast((a0[0] + a1[0]) + (a2[0] + a3[0]));
            float t1 = tanh_fast((a0[1] + a1[1]) + (a2[1] + a3[1]));
            float t2 = tanh_fast((a0[2] + a1[2]) + (a2[2] + a3[2]));
            float t3 = tanh_fast((a0[3] + a1[3]) + (a2[3] + a3[3]));
            storeT(w2, wbyte, t0, t1, t2, t3);
        }
        // L1(i) output (always real)
        float t0 = tanh_fast(u0[0] + u1[0] + u2[0]);
        float t1 = tanh_fast(u0[1] + u1[1] + u2[1]);
        float t2 = tanh_fast(u0[2] + u1[2] + u2[2]);
        float t3 = tanh_fast(u0[3] + u1[3] + u2[3]);
        storeT(w1, wbyte, t0, t1, t2, t3);
    } else {
        // L3(i-2) output (u-chain is a discarded dummy)
        if (Z3) {
            storeZ(w3, wbyte);
        } else {
            float t0 = tanh_fast((a0[0] + a1[0]) + (a2[0] + a3[0]));
            float t1 = tanh_fast((a0[1] + a1[1]) + (a2[1] + a3[1]));
            float t2 = tanh_fast((a0[2] + a1[2]) + (a2[2] + a3[2]));
            float t3 = tanh_fast((a0[3] + a1[3]) + (a2[3] + a3[3]));
            storeT(w3, wbyte, t0, t1, t2, t3);
        }
    }
    __syncthreads();
}

__global__ __launch_bounds__(512, 1)
void rnn3_kernel(const float* __restrict__ x,
                 const float* __restrict__ Wih1, const float* __restrict__ Whh1,
                 const float* __restrict__ bih1, const float* __restrict__ bhh1,
                 const float* __restrict__ Wih2, const float* __restrict__ Whh2,
                 const float* __restrict__ bih2, const float* __restrict__ bhh2,
                 const float* __restrict__ Wih3, const float* __restrict__ Whh3,
                 const float* __restrict__ bih3, const float* __restrict__ bhh3,
                 const float* __restrict__ Wfc,  const float* __restrict__ bfc,
                 float* __restrict__ out)
{
    __shared__ __align__(16) short h1s[2][2048];
    __shared__ __align__(16) short h2s[2][2048];
    __shared__ __align__(16) short h3s[2][2048];
    __shared__ float xls[514 * 17 + 8];   // x f32 stride-17; drain tail zeroed

    const int tid  = threadIdx.x;
    const int lane = tid & 63;
    const int w    = tid >> 6;        // 0..7
    const int stripe = w & 3;         // 16-col output stripe
    const bool isL12 = w < 4;         // wave role
    const int g    = lane >> 4;
    const int l15  = lane & 15;
    const int jrow = (stripe << 4) | l15;      // weight row (output col)
    const int bcol = l15;                      // batch row
    const int jout0 = (stripe << 4) + (g << 2);
    const int b0   = blockIdx.x * 16;

    // ---- zero-init all h buffers (h(-1)=0 + fill safety) ----
    { int* z1 = (int*)h1s; int* z2 = (int*)h2s; int* z3 = (int*)h3s;
      for (int k = tid; k < 2048; k += 512) { z1[k] = 0; z2[k] = 0; z3[k] = 0; } }

    // ---- stage x as f32 [t][b] (stride 17); zero the drain tail ----
    {
        const float4* xg = (const float4*)(x + (size_t)b0 * 512);
        for (int idx = tid; idx < 2048; idx += 512) {
            float4 v = xg[idx];
            int b = idx >> 7, t0 = (idx & 127) << 2;
            xls[(t0 + 0) * 17 + b] = v.x;
            xls[(t0 + 1) * 17 + b] = v.y;
            xls[(t0 + 2) * 17 + b] = v.z;
            xls[(t0 + 3) * 17 + b] = v.w;
        }
        if (tid < 42) xls[512 * 17 + tid] = 0.0f;   // covers phases 512/513 reads
    }

    // ---- per-wave weights ----
    // L12: A=Whh1, B=Wih2, C=Whh2, bF=b2, b1/w1f real. L3: A=0, B=Wih3, C=Whh3, bF=b3.
    const float* BW; const float* CW; const float* biF; const float* bhF;
    if (isL12) { BW = Wih2; CW = Whh2; biF = bih2; bhF = bhh2; }
    else       { BW = Wih3; CW = Whh3; biF = bih3; bhF = bhh3; }

    bf16x8 zf8 = {0,0,0,0,0,0,0,0};
    bf16x8 Ah0 = zf8, Al0 = zf8, Ah1 = zf8, Al1 = zf8;
    if (isL12) {
        makeA2(Whh1, jrow, (g << 3),      Ah0, Al0);
        makeA2(Whh1, jrow, 32 + (g << 3), Ah1, Al1);
    }
    bf16x8 Bh0, Bl0, Bh1, Bl1, Ch0, Cl0, Ch1, Cl1;
    makeA2(BW, jrow, (g << 3),      Bh0, Bl0);
    makeA2(BW, jrow, 32 + (g << 3), Bh1, Bl1);
    makeA2(CW, jrow, (g << 3),      Ch0, Cl0);
    makeA2(CW, jrow, 32 + (g << 3), Ch1, Cl1);

    f32x4 b1v, bFv, w1f;
#pragma unroll
    for (int r = 0; r < 4; ++r) {
        int j = jout0 + r;
        bool v = j < 50;
        bFv[r] = v ? (biF[j] + bhF[j]) : 0.0f;
        b1v[r] = (isL12 && v) ? (bih1[j] + bhh1[j]) : 0.0f;
        w1f[r] = (isL12 && v) ? Wih1[j] : 0.0f;
    }
    const f32x4 zc = {0.f, 0.f, 0.f, 0.f};

    const int wbyte = swz(bcol, jout0 << 1);

    __syncthreads();   // x staged, h zeroed

    // phase i: reads parity (i+1)&1, writes parity i&1.
    // phase 0: L1(0) real; L2/L3 outputs forced zero (= h(-1) states)
    phaseM<true, true>(h1s[1], h2s[1], h3s[1], h1s[0], h2s[0], h3s[0],
                       isL12, bcol, g, wbyte, xls[bcol],
                       b1v, bFv, w1f, Ah0, Ah1, Al0, Al1,
                       Bh0, Bh1, Bl0, Bl1, Ch0, Ch1, Cl0, Cl1, zc);
    // phase 1: L1(1), L2(0) real; L3 zero
    phaseM<false, true>(h1s[0], h2s[0], h3s[0], h1s[1], h2s[1], h3s[1],
                        isL12, bcol, g, wbyte, xls[17 + bcol],
                        b1v, bFv, w1f, Ah0, Ah1, Al0, Al1,
                        Bh0, Bh1, Bl0, Bl1, Ch0, Ch1, Cl0, Cl1, zc);

    // main phases 2..511 (manual 2x unroll, compile-time parities)
    for (int i = 2; i < 512; i += 2) {
        phaseM<false, false>(h1s[1], h2s[1], h3s[1], h1s[0], h2s[0], h3s[0],
                             isL12, bcol, g, wbyte, xls[i * 17 + bcol],
                             b1v, bFv, w1f, Ah0, Ah1, Al0, Al1,
                             Bh0, Bh1, Bl0, Bl1, Ch0, Ch1, Cl0, Cl1, zc);
        phaseM<false, false>(h1s[0], h2s[0], h3s[0], h1s[1], h2s[1], h3s[1],
                             isL12, bcol, g, wbyte, xls[(i + 1) * 17 + bcol],
                             b1v, bFv, w1f, Ah0, Ah1, Al0, Al1,
                             Bh0, Bh1, Bl0, Bl1, Ch0, Ch1, Cl0, Cl1, zc);
    }

    // drain: phase 512 (L2(511)->h2s[0], L3(510)->h3s[0]; L1 output finite, unused)
    phaseM<false, false>(h1s[1], h2s[1], h3s[1], h1s[0], h2s[0], h3s[0],
                         isL12, bcol, g, wbyte, xls[512 * 17 + bcol],
                         b1v, bFv, w1f, Ah0, Ah1, Al0, Al1,
                         Bh0, Bh1, Bl0, Bl1, Ch0, Ch1, Cl0, Cl1, zc);
    // drain: phase 513 (L3(511)->h3s[1]; other outputs finite, unused)
    phaseM<false, false>(h1s[0], h2s[0], h3s[0], h1s[1], h2s[1], h3s[1],
                         isL12, bcol, g, wbyte, xls[513 * 17 + bcol],
                         b1v, bFv, w1f, Ah0, Ah1, Al0, Al1,
                         Bh0, Bh1, Bl0, Bl1, Ch0, Ch1, Cl0, Cl1, zc);

    // ---- FC epilogue: out[b][o] = (h3_hi + h3_lo) @ Wfc^T + bfc ----
    if (w < 4) {
        const short* h3f = h3s[1];
        int o = (w << 2) | g;           // 0..15, valid < 10
        int b = bcol;
        if (o < 10) {
            float acc = bfc[o];
            for (int k = 0; k < 50; ++k)
                acc += (ldsR(h3f, b, k) + ldsR(h3f, b, 64 + k)) * Wfc[o * 50 + k];
            out[(size_t)(b0 + b) * 10 + o] = acc;
        }
    }
}

extern "C" void kernel_launch(void* const* d_in, const int* in_sizes, int n_in,
                              void* d_out, int out_size, void* d_ws, size_t ws_size,
                              hipStream_t stream) {
    const float* x    = (const float*)d_in[0];
    const float* Wih1 = (const float*)d_in[1];
    const float* Whh1 = (const float*)d_in[2];
    const float* bih1 = (const float*)d_in[3];
    const float* bhh1 = (const float*)d_in[4];
    const float* Wih2 = (const float*)d_in[5];
    const float* Whh2 = (const float*)d_in[6];
    const float* bih2 = (const float*)d_in[7];
    const float* bhh2 = (const float*)d_in[8];
    const float* Wih3 = (const float*)d_in[9];
    const float* Whh3 = (const float*)d_in[10];
    const float* bih3 = (const float*)d_in[11];
    const float* bhh3 = (const float*)d_in[12];
    const float* Wfc  = (const float*)d_in[13];
    const float* bfc  = (const float*)d_in[14];
    float* out = (float*)d_out;

    dim3 grid(256), block(512);   // 16 batch rows/block; 8 waves = {L12,L3} x stripe
    hipLaunchKernelGGL(rnn3_kernel, grid, block, 0, stream,
                       x, Wih1, Whh1, bih1, bhh1,
                       Wih2, Whh2, bih2, bhh2,
                       Wih3, Whh3, bih3, bhh3,
                       Wfc, bfc, out);
}

// Round 12
// 281.867 us; speedup vs baseline: 1.1453x; 1.1453x over previous
//
#include <hip/hip_runtime.h>

typedef __attribute__((ext_vector_type(8))) short bf16x8;
typedef __attribute__((ext_vector_type(4))) float f32x4;

// Operand-swapped GEMM: D^T = W (A-operand) * h^T (B-operand).
// WAVE SPECIALIZATION (r10): 12 waves = {L1,L2,L3} x 4 col-stripes, ONE barrier
// per phase. THIS ROUND: forward-input operands (h1 into L2, h2 into L3) are
// read HI-ONLY (single bf16) -- weights and recurrent-state operands keep the
// hi/lo split. Cuts full-layer waves from 8 reads/12 MFMAs to 6 reads/8 MFMAs
// while keeping 3 waves/SIMD of TLP.
#define MFMA(a, b, c) __builtin_amdgcn_mfma_f32_16x16x32_bf16((a), (b), (c), 0, 0, 0)

__device__ __forceinline__ short f2bf(float f) {
    union { float f; unsigned u; } v; v.f = f;
    unsigned r = v.u + 0x7fffu + ((v.u >> 16) & 1u);   // RNE
    return (short)(r >> 16);
}
__device__ __forceinline__ float bf2f(short h) {
    union { unsigned u; float f; } v;
    v.u = ((unsigned)(unsigned short)h) << 16;
    return v.f;
}
__device__ __forceinline__ void wsplit(float w, short& hi, short& lo) {
    hi = f2bf(w);
    lo = f2bf(w - bf2f(hi));
}
__device__ __forceinline__ float tanh_fast(float x) {
    float z = __builtin_amdgcn_exp2f(x * 2.8853900817779268f); // 2*log2(e)
    return 1.0f - 2.0f * __builtin_amdgcn_rcpf(z + 1.0f);
}
__device__ __forceinline__ unsigned cvt_pk_bf16(float a, float b) {
    unsigned r;
    asm("v_cvt_pk_bf16_f32 %0, %1, %2" : "=v"(r) : "v"(a), "v"(b));
    return r;
}

// weight fragment pair (hi + bf16 residual): element i = W[jrow][kbase+i], zero-padded
__device__ __forceinline__ void makeA2(const float* __restrict__ W, int jrow, int kbase,
                                       bf16x8& Ahi, bf16x8& Alo) {
#pragma unroll
    for (int i = 0; i < 8; ++i) {
        int m = kbase + i;
        short h = 0, l = 0;
        if (jrow < 50 && m < 50) wsplit(W[jrow * 50 + m], h, l);
        Ahi[i] = h; Alo[i] = l;
    }
}

// --- LDS h tile: [16 batch][128 hidden] bf16 (256B rows); cols 0-63 hi, 64-127 lo.
// XOR-swizzle bits 4-7 of byte-in-row with row (bijective).
// swz(row, b ^ 128) == swz(row, b) ^ 128 -> lo offset derived by XOR on the
// INTEGER offset (never +128, never XOR on a flat pointer).
__device__ __forceinline__ int swz(int row, int byteInRow) {
    return (row << 8) + (byteInRow ^ ((row & 15) << 4));
}
__device__ __forceinline__ bf16x8 ldsA(const short* buf, int row, int kblk, int g) {
    return *(const bf16x8*)((const char*)buf + swz(row, (kblk << 6) + (g << 4)));
}
__device__ __forceinline__ float ldsR(const short* buf, int row, int col) {
    return bf2f(*(const short*)((const char*)buf + swz(row, col << 1)));
}

// store 4 consecutive hidden cols (hi + lo residual) for this lane's batch row.
__device__ __forceinline__ void storeT(short* buf, int off, float t0, float t1, float t2, float t3) {
    unsigned h01 = cvt_pk_bf16(t0, t1);
    unsigned h23 = cvt_pk_bf16(t2, t3);
    float r0 = t0 - bf2f((short)h01);
    float r1 = t1 - bf2f((short)(h01 >> 16));
    float r2 = t2 - bf2f((short)h23);
    float r3 = t3 - bf2f((short)(h23 >> 16));
    unsigned l01 = cvt_pk_bf16(r0, r1);
    unsigned l23 = cvt_pk_bf16(r2, r3);
    uint2 hv; hv.x = h01; hv.y = h23;
    uint2 lv; lv.x = l01; lv.y = l23;
    *(uint2*)((char*)buf + off)         = hv;
    *(uint2*)((char*)buf + (off ^ 128)) = lv;
}
__device__ __forceinline__ void storeZ(short* buf, int off) {
    uint2 zz; zz.x = 0u; zz.y = 0u;
    *(uint2*)((char*)buf + off)         = zz;
    *(uint2*)((char*)buf + (off ^ 128)) = zz;
}

// Full two-matrix layer, input read HI-ONLY: 6 reads, 8 MFMAs, 4 chains of 2.
// Products kept: Ih*i_hi, Hh*s_hi, Hh*s_lo, Hl*s_hi (input-lo products dropped).
template<bool ZOUT>
__device__ __forceinline__ void layerW_full(
    const short* rIn, const short* rState, short* wOut,
    int bcol, int g, int wbyte,
    const bf16x8& Ih0, const bf16x8& Ih1,
    const bf16x8& Hh0, const bf16x8& Hh1, const bf16x8& Hl0, const bf16x8& Hl1,
    const f32x4& bias, const f32x4& zc)
{
    bf16x8 i0 = ldsA(rIn, bcol, 0, g), i1 = ldsA(rIn, bcol, 1, g);
    bf16x8 s0 = ldsA(rState, bcol, 0, g), s1 = ldsA(rState, bcol, 1, g);
    bf16x8 s2 = ldsA(rState, bcol, 2, g), s3 = ldsA(rState, bcol, 3, g);
    __builtin_amdgcn_s_setprio(1);
    f32x4 a0 = MFMA(Ih0, i0, bias);
    f32x4 a1 = MFMA(Hh0, s0, zc);
    f32x4 a2 = MFMA(Hh0, s2, zc);   // hi-W x lo-state
    f32x4 a3 = MFMA(Hl0, s0, zc);   // lo-W x hi-state
    a0 = MFMA(Ih1, i1, a0);
    a1 = MFMA(Hh1, s1, a1);
    a2 = MFMA(Hh1, s3, a2);
    a3 = MFMA(Hl1, s1, a3);
    __builtin_amdgcn_s_setprio(0);
    if (ZOUT) {
        storeZ(wOut, wbyte);
    } else {
        float t0 = tanh_fast((a0[0] + a1[0]) + (a2[0] + a3[0]));
        float t1 = tanh_fast((a0[1] + a1[1]) + (a2[1] + a3[1]));
        float t2 = tanh_fast((a0[2] + a1[2]) + (a2[2] + a3[2]));
        float t3 = tanh_fast((a0[3] + a1[3]) + (a2[3] + a3[3]));
        storeT(wOut, wbyte, t0, t1, t2, t3);
    }
}

// L1 layer: recurrence state keeps FULL hi/lo split (4 reads, 6 MFMAs).
__device__ __forceinline__ void layerW_one(
    const short* r1, short* w1,
    int bcol, int g, int wbyte,
    const bf16x8& Hh0, const bf16x8& Hh1, const bf16x8& Hl0, const bf16x8& Hl1,
    const f32x4& c1i, const f32x4& zc)
{
    bf16x8 s0 = ldsA(r1, bcol, 0, g), s1 = ldsA(r1, bcol, 1, g);
    bf16x8 s2 = ldsA(r1, bcol, 2, g), s3 = ldsA(r1, bcol, 3, g);
    __builtin_amdgcn_s_setprio(1);
    f32x4 u0 = MFMA(Hh0, s0, c1i);
    f32x4 u1 = MFMA(Hh0, s2, zc);
    f32x4 u2 = MFMA(Hl0, s0, zc);
    u0 = MFMA(Hh1, s1, u0);
    u1 = MFMA(Hh1, s3, u1);
    u2 = MFMA(Hl1, s1, u2);
    __builtin_amdgcn_s_setprio(0);
    float t0 = tanh_fast(u0[0] + u1[0] + u2[0]);
    float t1 = tanh_fast(u0[1] + u1[1] + u2[1]);
    float t2 = tanh_fast(u0[2] + u1[2] + u2[2]);
    float t3 = tanh_fast(u0[3] + u1[3] + u2[3]);
    storeT(w1, wbyte, t0, t1, t2, t3);
}

// One phase: wave-uniform dispatch by layerid, ONE barrier at the end.
// reads r* (prev parity), writes w* (this parity).
template<bool Z2, bool Z3>
__device__ __forceinline__ void phaseW(
    const short* r1, const short* r2, const short* r3,
    short* w1, short* w2, short* w3,
    int layerid, int bcol, int g, int wbyte, const float* xrow,
    const f32x4& bv, const f32x4& w1f,
    const bf16x8& Ih0, const bf16x8& Ih1,
    const bf16x8& Hh0, const bf16x8& Hh1, const bf16x8& Hl0, const bf16x8& Hl1,
    const f32x4& zc)
{
    if (layerid == 0) {
        float xf = xrow[bcol];
        f32x4 c1i;
        c1i[0] = fmaf(w1f[0], xf, bv[0]);
        c1i[1] = fmaf(w1f[1], xf, bv[1]);
        c1i[2] = fmaf(w1f[2], xf, bv[2]);
        c1i[3] = fmaf(w1f[3], xf, bv[3]);
        layerW_one(r1, w1, bcol, g, wbyte, Hh0, Hh1, Hl0, Hl1, c1i, zc);
    } else if (layerid == 1) {
        // L2(i-1): input h1(prev) hi-only, state h2(prev) split
        layerW_full<Z2>(r1, r2, w2, bcol, g, wbyte,
                        Ih0, Ih1, Hh0, Hh1, Hl0, Hl1, bv, zc);
    } else {
        // L3(i-2): input h2(prev) hi-only, state h3(prev) split
        layerW_full<Z3>(r2, r3, w3, bcol, g, wbyte,
                        Ih0, Ih1, Hh0, Hh1, Hl0, Hl1, bv, zc);
    }
    __syncthreads();
}

__global__ __launch_bounds__(768, 1)
void rnn3_kernel(const float* __restrict__ x,
                 const float* __restrict__ Wih1, const float* __restrict__ Whh1,
                 const float* __restrict__ bih1, const float* __restrict__ bhh1,
                 const float* __restrict__ Wih2, const float* __restrict__ Whh2,
                 const float* __restrict__ bih2, const float* __restrict__ bhh2,
                 const float* __restrict__ Wih3, const float* __restrict__ Whh3,
                 const float* __restrict__ bih3, const float* __restrict__ bhh3,
                 const float* __restrict__ Wfc,  const float* __restrict__ bfc,
                 float* __restrict__ out)
{
    __shared__ __align__(16) short h1s[2][2048];
    __shared__ __align__(16) short h2s[2][2048];
    __shared__ __align__(16) short h3s[2][2048];
    __shared__ float xls[514 * 17 + 8];   // x f32 stride-17; drain tail zeroed

    const int tid  = threadIdx.x;
    const int lane = tid & 63;
    const int w    = tid >> 6;        // 0..11
    const int stripe  = w & 3;        // 16-col output stripe
    const int layerid = w >> 2;       // 0 = L1, 1 = L2, 2 = L3
    const int g    = lane >> 4;
    const int l15  = lane & 15;
    const int jrow = (stripe << 4) | l15;      // weight row (output col)
    const int bcol = l15;                      // batch row
    const int jout0 = (stripe << 4) + (g << 2);
    const int b0   = blockIdx.x * 16;

    // ---- zero-init all h buffers (h(-1)=0 + fill safety) ----
    { int* z1 = (int*)h1s; int* z2 = (int*)h2s; int* z3 = (int*)h3s;
      for (int k = tid; k < 2048; k += 768) { z1[k] = 0; z2[k] = 0; z3[k] = 0; } }

    // ---- stage x as f32 [t][b] (stride 17); zero the drain tail ----
    {
        const float4* xg = (const float4*)(x + (size_t)b0 * 512);
        for (int idx = tid; idx < 2048; idx += 768) {
            float4 v = xg[idx];
            int b = idx >> 7, t0 = (idx & 127) << 2;
            xls[(t0 + 0) * 17 + b] = v.x;
            xls[(t0 + 1) * 17 + b] = v.y;
            xls[(t0 + 2) * 17 + b] = v.z;
            xls[(t0 + 3) * 17 + b] = v.w;
        }
        if (tid < 42) xls[512 * 17 + tid] = 0.0f;   // covers phases 512/513 reads
    }

    // ---- per-wave weights: ONLY this wave's layer ----
    const float* WI; const float* WH; const float* bi; const float* bh;
    if (layerid == 0)      { WI = Wih1; WH = Whh1; bi = bih1; bh = bhh1; }
    else if (layerid == 1) { WI = Wih2; WH = Whh2; bi = bih2; bh = bhh2; }
    else                   { WI = Wih3; WH = Whh3; bi = bih3; bh = bhh3; }

    bf16x8 zf8 = {0,0,0,0,0,0,0,0};
    bf16x8 Ih0 = zf8, Ih1 = zf8;
    bf16x8 Hh0, Hl0, Hh1, Hl1;
    makeA2(WH, jrow, (g << 3),      Hh0, Hl0);
    makeA2(WH, jrow, 32 + (g << 3), Hh1, Hl1);
    if (layerid != 0) {
        // input-side weight: hi only (lo residual product dropped by design)
        bf16x8 t0, t1;
        makeA2(WI, jrow, (g << 3),      Ih0, t0);
        makeA2(WI, jrow, 32 + (g << 3), Ih1, t1);
    }

    f32x4 bv, w1f;
#pragma unroll
    for (int r = 0; r < 4; ++r) {
        int j = jout0 + r;
        bool v = j < 50;
        bv[r]  = v ? (bi[j] + bh[j]) : 0.0f;
        w1f[r] = (layerid == 0 && v) ? Wih1[j] : 0.0f;
    }
    const f32x4 zc = {0.f, 0.f, 0.f, 0.f};

    const int wbyte = swz(bcol, jout0 << 1);

    __syncthreads();   // x staged, h zeroed

    // phase i: reads parity (i+1)&1, writes parity i&1.
    // phase 0: L1(0) real; L2/L3 write zeros (= h(-1) states)
    phaseW<true, true>(h1s[1], h2s[1], h3s[1], h1s[0], h2s[0], h3s[0],
                       layerid, bcol, g, wbyte, &xls[0],
                       bv, w1f, Ih0, Ih1, Hh0, Hh1, Hl0, Hl1, zc);
    // phase 1: L1(1), L2(0) real; L3 writes zero
    phaseW<false, true>(h1s[0], h2s[0], h3s[0], h1s[1], h2s[1], h3s[1],
                        layerid, bcol, g, wbyte, &xls[17],
                        bv, w1f, Ih0, Ih1, Hh0, Hh1, Hl0, Hl1, zc);

    // main phases 2..511 (manual 2x unroll, compile-time parities)
    for (int i = 2; i < 512; i += 2) {
        phaseW<false, false>(h1s[1], h2s[1], h3s[1], h1s[0], h2s[0], h3s[0],
                             layerid, bcol, g, wbyte, &xls[i * 17],
                             bv, w1f, Ih0, Ih1, Hh0, Hh1, Hl0, Hl1, zc);
        phaseW<false, false>(h1s[0], h2s[0], h3s[0], h1s[1], h2s[1], h3s[1],
                             layerid, bcol, g, wbyte, &xls[(i + 1) * 17],
                             bv, w1f, Ih0, Ih1, Hh0, Hh1, Hl0, Hl1, zc);
    }

    // drain: phase 512 (L2(511)->h2s[0], L3(510)->h3s[0]; L1 output finite, unused)
    phaseW<false, false>(h1s[1], h2s[1], h3s[1], h1s[0], h2s[0], h3s[0],
                         layerid, bcol, g, wbyte, &xls[512 * 17],
                         bv, w1f, Ih0, Ih1, Hh0, Hh1, Hl0, Hl1, zc);
    // drain: phase 513 (L3(511)->h3s[1]; other outputs finite, unused)
    phaseW<false, false>(h1s[0], h2s[0], h3s[0], h1s[1], h2s[1], h3s[1],
                         layerid, bcol, g, wbyte, &xls[513 * 17],
                         bv, w1f, Ih0, Ih1, Hh0, Hh1, Hl0, Hl1, zc);

    // ---- FC epilogue: out[b][o] = (h3_hi + h3_lo) @ Wfc^T + bfc ----
    if (w < 4) {
        const short* h3f = h3s[1];
        int o = (w << 2) | g;           // 0..15, valid < 10
        int b = bcol;
        if (o < 10) {
            float acc = bfc[o];
            for (int k = 0; k < 50; ++k)
                acc += (ldsR(h3f, b, k) + ldsR(h3f, b, 64 + k)) * Wfc[o * 50 + k];
            out[(size_t)(b0 + b) * 10 + o] = acc;
        }
    }
}

extern "C" void kernel_launch(void* const* d_in, const int* in_sizes, int n_in,
                              void* d_out, int out_size, void* d_ws, size_t ws_size,
                              hipStream_t stream) {
    const float* x    = (const float*)d_in[0];
    const float* Wih1 = (const float*)d_in[1];
    const float* Whh1 = (const float*)d_in[2];
    const float* bih1 = (const float*)d_in[3];
    const float* bhh1 = (const float*)d_in[4];
    const float* Wih2 = (const float*)d_in[5];
    const float* Whh2 = (const float*)d_in[6];
    const float* bih2 = (const float*)d_in[7];
    const float* bhh2 = (const float*)d_in[8];
    const float* Wih3 = (const float*)d_in[9];
    const float* Whh3 = (const float*)d_in[10];
    const float* bih3 = (const float*)d_in[11];
    const float* bhh3 = (const float*)d_in[12];
    const float* Wfc  = (const float*)d_in[13];
    const float* bfc  = (const float*)d_in[14];
    float* out = (float*)d_out;

    dim3 grid(256), block(768);   // 16 batch rows/block; 12 waves = layer x stripe
    hipLaunchKernelGGL(rnn3_kernel, grid, block, 0, stream,
                       x, Wih1, Whh1, bih1, bhh1,
                       Wih2, Whh2, bih2, bhh2,
                       Wih3, Whh3, bih3, bhh3,
                       Wfc, bfc, out);
}

// Round 13
// 249.783 us; speedup vs baseline: 1.2924x; 1.1284x over previous
//
#include <hip/hip_runtime.h>

typedef __attribute__((ext_vector_type(8))) short bf16x8;
typedef __attribute__((ext_vector_type(4))) float f32x4;

// Operand-swapped GEMM: D^T = W (A-operand) * h^T (B-operand).
// 12 waves = {L1,L2,L3} x 4 col-stripes, ONE barrier/phase (r10-r12 proven).
// This round: all LDS addresses precomputed loop-invariant (single fused hall
// buffer + byte offsets), weights prescaled by 2*log2(e) so tanh drops its
// multiply, and 2 accumulation chains per layer (fewer adds / AGPR traffic).
#define MFMA(a, b, c) __builtin_amdgcn_mfma_f32_16x16x32_bf16((a), (b), (c), 0, 0, 0)

#define TANH_SCALE 2.8853900817779268f   // 2*log2(e); folded into weights

__device__ __forceinline__ short f2bf(float f) {
    union { float f; unsigned u; } v; v.f = f;
    unsigned r = v.u + 0x7fffu + ((v.u >> 16) & 1u);   // RNE
    return (short)(r >> 16);
}
__device__ __forceinline__ float bf2f(short h) {
    union { unsigned u; float f; } v;
    v.u = ((unsigned)(unsigned short)h) << 16;
    return v.f;
}
__device__ __forceinline__ void wsplit(float w, short& hi, short& lo) {
    hi = f2bf(w);
    lo = f2bf(w - bf2f(hi));
}
// tanh on a PRESCALED accumulator s = 2*log2(e)*y:  tanh(y) = 1 - 2/(2^s + 1)
__device__ __forceinline__ float tanh_ps(float s) {
    float z = __builtin_amdgcn_exp2f(s);
    return fmaf(-2.0f, __builtin_amdgcn_rcpf(z + 1.0f), 1.0f);
}
__device__ __forceinline__ unsigned cvt_pk_bf16(float a, float b) {
    unsigned r;
    asm("v_cvt_pk_bf16_f32 %0, %1, %2" : "=v"(r) : "v"(a), "v"(b));
    return r;
}

// weight fragment pair (hi + bf16 residual) of SCALED weight, zero-padded
__device__ __forceinline__ void makeA2(const float* __restrict__ W, int jrow, int kbase,
                                       bf16x8& Ahi, bf16x8& Alo) {
#pragma unroll
    for (int i = 0; i < 8; ++i) {
        int m = kbase + i;
        short h = 0, l = 0;
        if (jrow < 50 && m < 50) wsplit(W[jrow * 50 + m] * TANH_SCALE, h, l);
        Ahi[i] = h; Alo[i] = l;
    }
}

// --- LDS h tile: [16 batch][128 hidden] bf16 (256B rows); cols 0-63 hi, 64-127 lo.
// XOR-swizzle bits 4-7 of byte-in-row with row (bijective).
// swz(row, b ^ 128) == swz(row, b) ^ 128 -> lo offset via XOR on the INT offset.
__device__ __forceinline__ int swz(int row, int byteInRow) {
    return (row << 8) + (byteInRow ^ ((row & 15) << 4));
}
__device__ __forceinline__ bf16x8 ldsO(const short* hall, int off) {
    return *(const bf16x8*)((const char*)hall + off);
}
__device__ __forceinline__ float ldsR(const short* buf, int row, int col) {
    return bf2f(*(const short*)((const char*)buf + swz(row, col << 1)));
}

// store 4 consecutive hidden cols (hi + lo residual) at precomputed offset.
__device__ __forceinline__ void storeT(short* hall, int off, float t0, float t1, float t2, float t3) {
    unsigned h01 = cvt_pk_bf16(t0, t1);
    unsigned h23 = cvt_pk_bf16(t2, t3);
    float r0 = t0 - bf2f((short)h01);
    float r1 = t1 - bf2f((short)(h01 >> 16));
    float r2 = t2 - bf2f((short)h23);
    float r3 = t3 - bf2f((short)(h23 >> 16));
    unsigned l01 = cvt_pk_bf16(r0, r1);
    unsigned l23 = cvt_pk_bf16(r2, r3);
    uint2 hv; hv.x = h01; hv.y = h23;
    uint2 lv; lv.x = l01; lv.y = l23;
    *(uint2*)((char*)hall + off)         = hv;
    *(uint2*)((char*)hall + (off ^ 128)) = lv;
}
__device__ __forceinline__ void storeZ(short* hall, int off) {
    uint2 zz; zz.x = 0u; zz.y = 0u;
    *(uint2*)((char*)hall + off)         = zz;
    *(uint2*)((char*)hall + (off ^ 128)) = zz;
}

// One phase, role-dispatched; ALL addresses are precomputed byte offsets.
// L2/L3 (full layer, hi-only input, r12 product set): 6 reads, 8 MFMAs in 2
// chains of 4. L1: 4 reads, 6 MFMAs in 2 chains of 3, x folded into C-init.
// ONE barrier at phase end (parity/Z scheme identical to r12).
template<bool ZOUT>
__device__ __forceinline__ void phaseX(
    short* hall, int layerid,
    int i0o, int i1o, int s0o, int s1o, int s2o, int s3o, int woff,
    const float* xrow, int bcol,
    const f32x4& bv, const f32x4& w1f,
    const bf16x8& Ih0, const bf16x8& Ih1,
    const bf16x8& Hh0, const bf16x8& Hh1, const bf16x8& Hl0, const bf16x8& Hl1,
    const f32x4& zc)
{
    if (layerid == 0) {
        float xf = xrow[bcol];
        f32x4 c1i;
        c1i[0] = fmaf(w1f[0], xf, bv[0]);
        c1i[1] = fmaf(w1f[1], xf, bv[1]);
        c1i[2] = fmaf(w1f[2], xf, bv[2]);
        c1i[3] = fmaf(w1f[3], xf, bv[3]);
        bf16x8 s0 = ldsO(hall, s0o), s1 = ldsO(hall, s1o);
        bf16x8 s2 = ldsO(hall, s2o), s3 = ldsO(hall, s3o);
        f32x4 c0 = MFMA(Hh0, s0, c1i);
        f32x4 c1 = MFMA(Hh0, s2, zc);
        c0 = MFMA(Hh1, s1, c0);
        c1 = MFMA(Hh1, s3, c1);
        c0 = MFMA(Hl0, s0, c0);
        c1 = MFMA(Hl1, s1, c1);
        float t0 = tanh_ps(c0[0] + c1[0]);
        float t1 = tanh_ps(c0[1] + c1[1]);
        float t2 = tanh_ps(c0[2] + c1[2]);
        float t3 = tanh_ps(c0[3] + c1[3]);
        storeT(hall, woff, t0, t1, t2, t3);
    } else {
        bf16x8 i0 = ldsO(hall, i0o), i1 = ldsO(hall, i1o);
        bf16x8 s0 = ldsO(hall, s0o), s1 = ldsO(hall, s1o);
        bf16x8 s2 = ldsO(hall, s2o), s3 = ldsO(hall, s3o);
        f32x4 c0 = MFMA(Ih0, i0, bv);
        f32x4 c1 = MFMA(Hh0, s0, zc);
        c0 = MFMA(Ih1, i1, c0);
        c1 = MFMA(Hh1, s1, c1);
        c0 = MFMA(Hh0, s2, c0);   // hi-W x lo-state
        c1 = MFMA(Hl0, s0, c1);   // lo-W x hi-state
        c0 = MFMA(Hh1, s3, c0);
        c1 = MFMA(Hl1, s1, c1);
        if (ZOUT) {
            storeZ(hall, woff);
        } else {
            float t0 = tanh_ps(c0[0] + c1[0]);
            float t1 = tanh_ps(c0[1] + c1[1]);
            float t2 = tanh_ps(c0[2] + c1[2]);
            float t3 = tanh_ps(c0[3] + c1[3]);
            storeT(hall, woff, t0, t1, t2, t3);
        }
    }
    __syncthreads();
}

__global__ __launch_bounds__(768, 1)
void rnn3_kernel(const float* __restrict__ x,
                 const float* __restrict__ Wih1, const float* __restrict__ Whh1,
                 const float* __restrict__ bih1, const float* __restrict__ bhh1,
                 const float* __restrict__ Wih2, const float* __restrict__ Whh2,
                 const float* __restrict__ bih2, const float* __restrict__ bhh2,
                 const float* __restrict__ Wih3, const float* __restrict__ Whh3,
                 const float* __restrict__ bih3, const float* __restrict__ bhh3,
                 const float* __restrict__ Wfc,  const float* __restrict__ bfc,
                 float* __restrict__ out)
{
    // fused state buffer: region r = buf*2 + parity (buf: 0=h1, 1=h2, 2=h3),
    // each region 4096 bytes = [16][128] bf16 swizzled tile.
    __shared__ __align__(16) short hall[6][2048];
    __shared__ float xls[514 * 17 + 8];   // x f32 stride-17; drain tail zeroed

    const int tid  = threadIdx.x;
    const int lane = tid & 63;
    const int w    = tid >> 6;        // 0..11
    const int stripe  = w & 3;        // 16-col output stripe
    const int layerid = w >> 2;       // 0 = L1, 1 = L2, 2 = L3
    const int g    = lane >> 4;
    const int l15  = lane & 15;
    const int jrow = (stripe << 4) | l15;      // weight row (output col)
    const int bcol = l15;                      // batch row
    const int jout0 = (stripe << 4) + (g << 2);
    const int b0   = blockIdx.x * 16;

    // ---- zero-init all h regions (h(-1)=0 + fill safety) ----
    { int* z = (int*)hall; for (int k = tid; k < 6144; k += 768) z[k] = 0; }

    // ---- stage x as f32 [t][b] (stride 17); zero the drain tail ----
    {
        const float4* xg = (const float4*)(x + (size_t)b0 * 512);
        for (int idx = tid; idx < 2048; idx += 768) {
            float4 v = xg[idx];
            int b = idx >> 7, t0 = (idx & 127) << 2;
            xls[(t0 + 0) * 17 + b] = v.x;
            xls[(t0 + 1) * 17 + b] = v.y;
            xls[(t0 + 2) * 17 + b] = v.z;
            xls[(t0 + 3) * 17 + b] = v.w;
        }
        if (tid < 42) xls[512 * 17 + tid] = 0.0f;   // covers phases 512/513 reads
    }

    // ---- per-wave weights (prescaled by 2*log2(e)) ----
    const float* WI; const float* WH; const float* bi; const float* bh;
    if (layerid == 0)      { WI = Wih1; WH = Whh1; bi = bih1; bh = bhh1; }
    else if (layerid == 1) { WI = Wih2; WH = Whh2; bi = bih2; bh = bhh2; }
    else                   { WI = Wih3; WH = Whh3; bi = bih3; bh = bhh3; }

    bf16x8 zf8 = {0,0,0,0,0,0,0,0};
    bf16x8 Ih0 = zf8, Ih1 = zf8;
    bf16x8 Hh0, Hl0, Hh1, Hl1;
    makeA2(WH, jrow, (g << 3),      Hh0, Hl0);
    makeA2(WH, jrow, 32 + (g << 3), Hh1, Hl1);
    if (layerid != 0) {
        bf16x8 d0, d1;   // input-side lo residual dropped by design (r12)
        makeA2(WI, jrow, (g << 3),      Ih0, d0);
        makeA2(WI, jrow, 32 + (g << 3), Ih1, d1);
    }

    f32x4 bv, w1f;
#pragma unroll
    for (int r = 0; r < 4; ++r) {
        int j = jout0 + r;
        bool v = j < 50;
        bv[r]  = v ? ((bi[j] + bh[j]) * TANH_SCALE) : 0.0f;
        w1f[r] = (layerid == 0 && v) ? (Wih1[j] * TANH_SCALE) : 0.0f;
    }
    const f32x4 zc = {0.f, 0.f, 0.f, 0.f};

    // ---- loop-invariant byte offsets ----
    // lane-local swizzled offsets within a region, kblk 0..3
    const int o0 = swz(bcol, (0 << 6) + (g << 4));
    const int o1 = swz(bcol, (1 << 6) + (g << 4));
    const int o2 = swz(bcol, (2 << 6) + (g << 4));
    const int o3 = swz(bcol, (3 << 6) + (g << 4));
    const int wbyte = swz(bcol, jout0 << 1);
    // role-specific buffers: input buf (L2<-h1=0, L3<-h2=1), state buf = layerid
    const int inb = (layerid == 2) ? 1 : 0;
    const int stb = layerid;
    // phase writing parity 0 reads parity 1, and vice versa
    const int A_i0 = (inb * 2 + 1) * 4096 + o0, A_i1 = (inb * 2 + 1) * 4096 + o1;
    const int A_s0 = (stb * 2 + 1) * 4096 + o0, A_s1 = (stb * 2 + 1) * 4096 + o1;
    const int A_s2 = (stb * 2 + 1) * 4096 + o2, A_s3 = (stb * 2 + 1) * 4096 + o3;
    const int B_i0 = (inb * 2 + 0) * 4096 + o0, B_i1 = (inb * 2 + 0) * 4096 + o1;
    const int B_s0 = (stb * 2 + 0) * 4096 + o0, B_s1 = (stb * 2 + 0) * 4096 + o1;
    const int B_s2 = (stb * 2 + 0) * 4096 + o2, B_s3 = (stb * 2 + 0) * 4096 + o3;
    const int wofA = (layerid * 2 + 0) * 4096 + wbyte;   // write parity 0
    const int wofB = (layerid * 2 + 1) * 4096 + wbyte;   // write parity 1

    __syncthreads();   // x staged, h zeroed

    // phase i: reads parity (i+1)&1, writes parity i&1 (r12 schedule).
    // phase 0 (write par0): L1 real; L2/L3 write zeros (= h(-1) states)
    phaseX<true>(&hall[0][0], layerid, A_i0, A_i1, A_s0, A_s1, A_s2, A_s3, wofA,
                 &xls[0], bcol, bv, w1f, Ih0, Ih1, Hh0, Hh1, Hl0, Hl1, zc);
    // phase 1 (write par1): L1, L2 real; L3 zero
    if (layerid == 2) {
        phaseX<true>(&hall[0][0], layerid, B_i0, B_i1, B_s0, B_s1, B_s2, B_s3, wofB,
                     &xls[17], bcol, bv, w1f, Ih0, Ih1, Hh0, Hh1, Hl0, Hl1, zc);
    } else {
        phaseX<false>(&hall[0][0], layerid, B_i0, B_i1, B_s0, B_s1, B_s2, B_s3, wofB,
                      &xls[17], bcol, bv, w1f, Ih0, Ih1, Hh0, Hh1, Hl0, Hl1, zc);
    }

    // main phases 2..511 (manual 2x unroll, compile-time parities)
    for (int i = 2; i < 512; i += 2) {
        phaseX<false>(&hall[0][0], layerid, A_i0, A_i1, A_s0, A_s1, A_s2, A_s3, wofA,
                      &xls[i * 17], bcol, bv, w1f, Ih0, Ih1, Hh0, Hh1, Hl0, Hl1, zc);
        phaseX<false>(&hall[0][0], layerid, B_i0, B_i1, B_s0, B_s1, B_s2, B_s3, wofB,
                      &xls[(i + 1) * 17], bcol, bv, w1f, Ih0, Ih1, Hh0, Hh1, Hl0, Hl1, zc);
    }

    // drain: phase 512 (L2(511), L3(510); L1 output finite, unused)
    phaseX<false>(&hall[0][0], layerid, A_i0, A_i1, A_s0, A_s1, A_s2, A_s3, wofA,
                  &xls[512 * 17], bcol, bv, w1f, Ih0, Ih1, Hh0, Hh1, Hl0, Hl1, zc);
    // drain: phase 513 (L3(511) -> h3 parity 1)
    phaseX<false>(&hall[0][0], layerid, B_i0, B_i1, B_s0, B_s1, B_s2, B_s3, wofB,
                  &xls[513 * 17], bcol, bv, w1f, Ih0, Ih1, Hh0, Hh1, Hl0, Hl1, zc);

    // ---- FC epilogue: out[b][o] = (h3_hi + h3_lo) @ Wfc^T + bfc ----
    if (w < 4) {
        const short* h3f = &hall[5][0];   // h3, parity 1 (phase 513's write)
        int o = (w << 2) | g;             // 0..15, valid < 10
        int b = bcol;
        if (o < 10) {
            float acc = bfc[o];
            for (int k = 0; k < 50; ++k)
                acc += (ldsR(h3f, b, k) + ldsR(h3f, b, 64 + k)) * Wfc[o * 50 + k];
            out[(size_t)(b0 + b) * 10 + o] = acc;
        }
    }
}

extern "C" void kernel_launch(void* const* d_in, const int* in_sizes, int n_in,
                              void* d_out, int out_size, void* d_ws, size_t ws_size,
                              hipStream_t stream) {
    const float* x    = (const float*)d_in[0];
    const float* Wih1 = (const float*)d_in[1];
    const float* Whh1 = (const float*)d_in[2];
    const float* bih1 = (const float*)d_in[3];
    const float* bhh1 = (const float*)d_in[4];
    const float* Wih2 = (const float*)d_in[5];
    const float* Whh2 = (const float*)d_in[6];
    const float* bih2 = (const float*)d_in[7];
    const float* bhh2 = (const float*)d_in[8];
    const float* Wih3 = (const float*)d_in[9];
    const float* Whh3 = (const float*)d_in[10];
    const float* bih3 = (const float*)d_in[11];
    const float* bhh3 = (const float*)d_in[12];
    const float* Wfc  = (const float*)d_in[13];
    const float* bfc  = (const float*)d_in[14];
    float* out = (float*)d_out;

    dim3 grid(256), block(768);   // 16 batch rows/block; 12 waves = layer x stripe
    hipLaunchKernelGGL(rnn3_kernel, grid, block, 0, stream,
                       x, Wih1, Whh1, bih1, bhh1,
                       Wih2, Whh2, bih2, bhh2,
                       Wih3, Whh3, bih3, bhh3,
                       Wfc, bfc, out);
}

// Round 14
// 184.740 us; speedup vs baseline: 1.7475x; 1.3521x over previous
//
#include <hip/hip_runtime.h>

typedef __attribute__((ext_vector_type(8))) short bf16x8;
typedef __attribute__((ext_vector_type(4))) float f32x4;

// Operand-swapped GEMM: D^T = W (A-operand) * h^T (B-operand).
// 12 waves = {L1,L2,L3} x 4 col-stripes, ONE barrier/phase (r10+ proven).
// r14: h states are SINGLE bf16 (no lo residual): weights keep hi/lo split,
// x folded in fp32, accumulation fp32. Cuts per-CU-phase LDS reads 64->40,
// MFMAs 88->64, and store packing cost. Layout unchanged (lo half unused).
#define MFMA(a, b, c) __builtin_amdgcn_mfma_f32_16x16x32_bf16((a), (b), (c), 0, 0, 0)

#define TANH_SCALE 2.8853900817779268f   // 2*log2(e); folded into weights

__device__ __forceinline__ short f2bf(float f) {
    union { float f; unsigned u; } v; v.f = f;
    unsigned r = v.u + 0x7fffu + ((v.u >> 16) & 1u);   // RNE
    return (short)(r >> 16);
}
__device__ __forceinline__ float bf2f(short h) {
    union { unsigned u; float f; } v;
    v.u = ((unsigned)(unsigned short)h) << 16;
    return v.f;
}
__device__ __forceinline__ void wsplit(float w, short& hi, short& lo) {
    hi = f2bf(w);
    lo = f2bf(w - bf2f(hi));
}
// tanh on a PRESCALED accumulator s = 2*log2(e)*y:  tanh(y) = 1 - 2/(2^s + 1)
__device__ __forceinline__ float tanh_ps(float s) {
    float z = __builtin_amdgcn_exp2f(s);
    return fmaf(-2.0f, __builtin_amdgcn_rcpf(z + 1.0f), 1.0f);
}
__device__ __forceinline__ unsigned cvt_pk_bf16(float a, float b) {
    unsigned r;
    asm("v_cvt_pk_bf16_f32 %0, %1, %2" : "=v"(r) : "v"(a), "v"(b));
    return r;
}

// weight fragment pair (hi + bf16 residual) of SCALED weight, zero-padded
__device__ __forceinline__ void makeA2(const float* __restrict__ W, int jrow, int kbase,
                                       bf16x8& Ahi, bf16x8& Alo) {
#pragma unroll
    for (int i = 0; i < 8; ++i) {
        int m = kbase + i;
        short h = 0, l = 0;
        if (jrow < 50 && m < 50) wsplit(W[jrow * 50 + m] * TANH_SCALE, h, l);
        Ahi[i] = h; Alo[i] = l;
    }
}

// --- LDS h tile: [16 batch][128 hidden-slot] bf16 (256B rows); cols 0-63 used.
// XOR-swizzle bits 4-7 of byte-in-row with row (bijective). Layout identical
// to r13 (lo half simply unused) to keep offsets byte-identical.
__device__ __forceinline__ int swz(int row, int byteInRow) {
    return (row << 8) + (byteInRow ^ ((row & 15) << 4));
}
__device__ __forceinline__ bf16x8 ldsO(const short* hall, int off) {
    return *(const bf16x8*)((const char*)hall + off);
}
__device__ __forceinline__ float ldsR(const short* buf, int row, int col) {
    return bf2f(*(const short*)((const char*)buf + swz(row, col << 1)));
}

// store 4 consecutive hidden cols (single bf16) at precomputed offset.
__device__ __forceinline__ void storeH(short* hall, int off, float t0, float t1, float t2, float t3) {
    uint2 hv;
    hv.x = cvt_pk_bf16(t0, t1);
    hv.y = cvt_pk_bf16(t2, t3);
    *(uint2*)((char*)hall + off) = hv;
}
__device__ __forceinline__ void storeZ(short* hall, int off) {
    uint2 zz; zz.x = 0u; zz.y = 0u;
    *(uint2*)((char*)hall + off) = zz;
}

// One phase, role-dispatched; ALL addresses are precomputed byte offsets.
// L2/L3: 4 reads (input hi, state hi), 6 MFMAs in 2 chains of 3.
// L1: 2 reads, 4 MFMAs in chains of 3+2 (x folded into C-init).
// ONE barrier at phase end (parity/Z scheme identical to r12/r13).
template<bool ZOUT>
__device__ __forceinline__ void phaseX(
    short* hall, int layerid,
    int i0o, int i1o, int s0o, int s1o, int woff,
    const float* xrow, int bcol,
    const f32x4& bv, const f32x4& w1f,
    const bf16x8& Ih0, const bf16x8& Ih1,
    const bf16x8& Hh0, const bf16x8& Hh1, const bf16x8& Hl0, const bf16x8& Hl1,
    const f32x4& zc)
{
    if (layerid == 0) {
        float xf = xrow[bcol];
        f32x4 c1i;
        c1i[0] = fmaf(w1f[0], xf, bv[0]);
        c1i[1] = fmaf(w1f[1], xf, bv[1]);
        c1i[2] = fmaf(w1f[2], xf, bv[2]);
        c1i[3] = fmaf(w1f[3], xf, bv[3]);
        bf16x8 s0 = ldsO(hall, s0o), s1 = ldsO(hall, s1o);
        f32x4 c0 = MFMA(Hh0, s0, c1i);
        f32x4 c1 = MFMA(Hh1, s1, zc);
        c0 = MFMA(Hl0, s0, c0);
        c1 = MFMA(Hl1, s1, c1);
        float t0 = tanh_ps(c0[0] + c1[0]);
        float t1 = tanh_ps(c0[1] + c1[1]);
        float t2 = tanh_ps(c0[2] + c1[2]);
        float t3 = tanh_ps(c0[3] + c1[3]);
        storeH(hall, woff, t0, t1, t2, t3);
    } else {
        bf16x8 i0 = ldsO(hall, i0o), i1 = ldsO(hall, i1o);
        bf16x8 s0 = ldsO(hall, s0o), s1 = ldsO(hall, s1o);
        f32x4 c0 = MFMA(Ih0, i0, bv);
        f32x4 c1 = MFMA(Ih1, i1, zc);
        c0 = MFMA(Hh0, s0, c0);
        c1 = MFMA(Hh1, s1, c1);
        c0 = MFMA(Hl0, s0, c0);
        c1 = MFMA(Hl1, s1, c1);
        if (ZOUT) {
            storeZ(hall, woff);
        } else {
            float t0 = tanh_ps(c0[0] + c1[0]);
            float t1 = tanh_ps(c0[1] + c1[1]);
            float t2 = tanh_ps(c0[2] + c1[2]);
            float t3 = tanh_ps(c0[3] + c1[3]);
            storeH(hall, woff, t0, t1, t2, t3);
        }
    }
    __syncthreads();
}

__global__ __launch_bounds__(768, 1)
void rnn3_kernel(const float* __restrict__ x,
                 const float* __restrict__ Wih1, const float* __restrict__ Whh1,
                 const float* __restrict__ bih1, const float* __restrict__ bhh1,
                 const float* __restrict__ Wih2, const float* __restrict__ Whh2,
                 const float* __restrict__ bih2, const float* __restrict__ bhh2,
                 const float* __restrict__ Wih3, const float* __restrict__ Whh3,
                 const float* __restrict__ bih3, const float* __restrict__ bhh3,
                 const float* __restrict__ Wfc,  const float* __restrict__ bfc,
                 float* __restrict__ out)
{
    // fused state buffer: region r = buf*2 + parity (buf: 0=h1, 1=h2, 2=h3),
    // each region 4096 bytes = [16][128] bf16 swizzled tile (cols 0-63 used).
    __shared__ __align__(16) short hall[6][2048];
    __shared__ float xls[514 * 17 + 8];   // x f32 stride-17; drain tail zeroed

    const int tid  = threadIdx.x;
    const int lane = tid & 63;
    const int w    = tid >> 6;        // 0..11
    const int stripe  = w & 3;        // 16-col output stripe
    const int layerid = w >> 2;       // 0 = L1, 1 = L2, 2 = L3
    const int g    = lane >> 4;
    const int l15  = lane & 15;
    const int jrow = (stripe << 4) | l15;      // weight row (output col)
    const int bcol = l15;                      // batch row
    const int jout0 = (stripe << 4) + (g << 2);
    const int b0   = blockIdx.x * 16;

    // ---- zero-init all h regions (h(-1)=0 + fill safety) ----
    { int* z = (int*)hall; for (int k = tid; k < 6144; k += 768) z[k] = 0; }

    // ---- stage x as f32 [t][b] (stride 17); zero the drain tail ----
    {
        const float4* xg = (const float4*)(x + (size_t)b0 * 512);
        for (int idx = tid; idx < 2048; idx += 768) {
            float4 v = xg[idx];
            int b = idx >> 7, t0 = (idx & 127) << 2;
            xls[(t0 + 0) * 17 + b] = v.x;
            xls[(t0 + 1) * 17 + b] = v.y;
            xls[(t0 + 2) * 17 + b] = v.z;
            xls[(t0 + 3) * 17 + b] = v.w;
        }
        if (tid < 42) xls[512 * 17 + tid] = 0.0f;   // covers phases 512/513 reads
    }

    // ---- per-wave weights (prescaled by 2*log2(e), hi + lo residual) ----
    const float* WI; const float* WH; const float* bi; const float* bh;
    if (layerid == 0)      { WI = Wih1; WH = Whh1; bi = bih1; bh = bhh1; }
    else if (layerid == 1) { WI = Wih2; WH = Whh2; bi = bih2; bh = bhh2; }
    else                   { WI = Wih3; WH = Whh3; bi = bih3; bh = bhh3; }

    bf16x8 zf8 = {0,0,0,0,0,0,0,0};
    bf16x8 Ih0 = zf8, Ih1 = zf8;
    bf16x8 Hh0, Hl0, Hh1, Hl1;
    makeA2(WH, jrow, (g << 3),      Hh0, Hl0);
    makeA2(WH, jrow, 32 + (g << 3), Hh1, Hl1);
    if (layerid != 0) {
        bf16x8 d0, d1;   // input-side lo residual dropped (r12)
        makeA2(WI, jrow, (g << 3),      Ih0, d0);
        makeA2(WI, jrow, 32 + (g << 3), Ih1, d1);
    }

    f32x4 bv, w1f;
#pragma unroll
    for (int r = 0; r < 4; ++r) {
        int j = jout0 + r;
        bool v = j < 50;
        bv[r]  = v ? ((bi[j] + bh[j]) * TANH_SCALE) : 0.0f;
        w1f[r] = (layerid == 0 && v) ? (Wih1[j] * TANH_SCALE) : 0.0f;
    }
    const f32x4 zc = {0.f, 0.f, 0.f, 0.f};

    // ---- loop-invariant byte offsets ----
    const int o0 = swz(bcol, (0 << 6) + (g << 4));   // hi, kblk 0
    const int o1 = swz(bcol, (1 << 6) + (g << 4));   // hi, kblk 1
    const int wbyte = swz(bcol, jout0 << 1);
    // role buffers: input buf (L2<-h1=0, L3<-h2=1), state buf = layerid
    const int inb = (layerid == 2) ? 1 : 0;
    const int stb = layerid;
    const int A_i0 = (inb * 2 + 1) * 4096 + o0, A_i1 = (inb * 2 + 1) * 4096 + o1;
    const int A_s0 = (stb * 2 + 1) * 4096 + o0, A_s1 = (stb * 2 + 1) * 4096 + o1;
    const int B_i0 = (inb * 2 + 0) * 4096 + o0, B_i1 = (inb * 2 + 0) * 4096 + o1;
    const int B_s0 = (stb * 2 + 0) * 4096 + o0, B_s1 = (stb * 2 + 0) * 4096 + o1;
    const int wofA = (layerid * 2 + 0) * 4096 + wbyte;   // write parity 0
    const int wofB = (layerid * 2 + 1) * 4096 + wbyte;   // write parity 1

    __syncthreads();   // x staged, h zeroed

    // phase i: reads parity (i+1)&1, writes parity i&1 (r12 schedule).
    // phase 0 (write par0): L1 real; L2/L3 write zeros (= h(-1) states)
    phaseX<true>(&hall[0][0], layerid, A_i0, A_i1, A_s0, A_s1, wofA,
                 &xls[0], bcol, bv, w1f, Ih0, Ih1, Hh0, Hh1, Hl0, Hl1, zc);
    // phase 1 (write par1): L1, L2 real; L3 zero
    if (layerid == 2) {
        phaseX<true>(&hall[0][0], layerid, B_i0, B_i1, B_s0, B_s1, wofB,
                     &xls[17], bcol, bv, w1f, Ih0, Ih1, Hh0, Hh1, Hl0, Hl1, zc);
    } else {
        phaseX<false>(&hall[0][0], layerid, B_i0, B_i1, B_s0, B_s1, wofB,
                      &xls[17], bcol, bv, w1f, Ih0, Ih1, Hh0, Hh1, Hl0, Hl1, zc);
    }

    // main phases 2..511 (manual 2x unroll, compile-time parities)
    for (int i = 2; i < 512; i += 2) {
        phaseX<false>(&hall[0][0], layerid, A_i0, A_i1, A_s0, A_s1, wofA,
                      &xls[i * 17], bcol, bv, w1f, Ih0, Ih1, Hh0, Hh1, Hl0, Hl1, zc);
        phaseX<false>(&hall[0][0], layerid, B_i0, B_i1, B_s0, B_s1, wofB,
                      &xls[(i + 1) * 17], bcol, bv, w1f, Ih0, Ih1, Hh0, Hh1, Hl0, Hl1, zc);
    }

    // drain: phase 512 (L2(511), L3(510); L1 output finite, unused)
    phaseX<false>(&hall[0][0], layerid, A_i0, A_i1, A_s0, A_s1, wofA,
                  &xls[512 * 17], bcol, bv, w1f, Ih0, Ih1, Hh0, Hh1, Hl0, Hl1, zc);
    // drain: phase 513 (L3(511) -> h3 parity 1)
    phaseX<false>(&hall[0][0], layerid, B_i0, B_i1, B_s0, B_s1, wofB,
                  &xls[513 * 17], bcol, bv, w1f, Ih0, Ih1, Hh0, Hh1, Hl0, Hl1, zc);

    // ---- FC epilogue: out[b][o] = h3 @ Wfc^T + bfc (h3 single bf16) ----
    if (w < 4) {
        const short* h3f = &hall[5][0];   // h3, parity 1 (phase 513's write)
        int o = (w << 2) | g;             // 0..15, valid < 10
        int b = bcol;
        if (o < 10) {
            float acc = bfc[o];
            for (int k = 0; k < 50; ++k)
                acc += ldsR(h3f, b, k) * Wfc[o * 50 + k];
            out[(size_t)(b0 + b) * 10 + o] = acc;
        }
    }
}

extern "C" void kernel_launch(void* const* d_in, const int* in_sizes, int n_in,
                              void* d_out, int out_size, void* d_ws, size_t ws_size,
                              hipStream_t stream) {
    const float* x    = (const float*)d_in[0];
    const float* Wih1 = (const float*)d_in[1];
    const float* Whh1 = (const float*)d_in[2];
    const float* bih1 = (const float*)d_in[3];
    const float* bhh1 = (const float*)d_in[4];
    const float* Wih2 = (const float*)d_in[5];
    const float* Whh2 = (const float*)d_in[6];
    const float* bih2 = (const float*)d_in[7];
    const float* bhh2 = (const float*)d_in[8];
    const float* Wih3 = (const float*)d_in[9];
    const float* Whh3 = (const float*)d_in[10];
    const float* bih3 = (const float*)d_in[11];
    const float* bhh3 = (const float*)d_in[12];
    const float* Wfc  = (const float*)d_in[13];
    const float* bfc  = (const float*)d_in[14];
    float* out = (float*)d_out;

    dim3 grid(256), block(768);   // 16 batch rows/block; 12 waves = layer x stripe
    hipLaunchKernelGGL(rnn3_kernel, grid, block, 0, stream,
                       x, Wih1, Whh1, bih1, bhh1,
                       Wih2, Whh2, bih2, bhh2,
                       Wih3, Whh3, bih3, bhh3,
                       Wfc, bfc, out);
}